// Round 4
// baseline (162.448 us; speedup 1.0000x reference)
//
#include <hip/hip_runtime.h>
#include <hip/hip_bf16.h>

// IndRNN forward: proj = x @ W + b  (K=D=256), then
// h_t = relu(proj_t + h_{t-1} * clip(u,0,1)) over T.
// R4: ONE fused kernel (plus tiny conv_wt). x is converted fp32->bf16
//     in-kernel by the stager waves (kills the conv_x pass and launch).
//     proj goes to a separate LDS buffer P (2 barriers/chunk instead of 3).
//     Per block (b, 128-unit slice): stage chunk (64 t) -> MFMA w/ W-frags
//     in VGPRs -> proj->P -> {waves 0-1 scan+store || waves 2-3 stage next}.

__device__ __forceinline__ unsigned short f2bf(float f) {
    unsigned int u = __float_as_uint(f);
    unsigned int r = (u + 0x7FFF + ((u >> 16) & 1)) >> 16;  // RNE
    return (unsigned short)r;
}

typedef __bf16 bf16x8 __attribute__((ext_vector_type(8)));
typedef float f32x4 __attribute__((ext_vector_type(4)));

// ------------------------------------------------------------ conv_wt
// W [K,N] fp32 -> Wt [N,K] bf16 (transpose), 256 KB total.
__global__ __launch_bounds__(256) void conv_wt(
    const float* __restrict__ W, unsigned short* __restrict__ Wt, int K, int N)
{
    int idx = blockIdx.x * blockDim.x + threadIdx.x;
    int kq = K >> 2;
    if (idx >= N * kq) return;
    int n = idx / kq;
    int k4 = (idx - n * kq) * 4;
    ushort4 o;
    o.x = f2bf(W[(long)(k4 + 0) * N + n]);
    o.y = f2bf(W[(long)(k4 + 1) * N + n]);
    o.z = f2bf(W[(long)(k4 + 2) * N + n]);
    o.w = f2bf(W[(long)(k4 + 3) * N + n]);
    *(ushort4*)(Wt + (long)n * K + k4) = o;
}

// ------------------------------------------------------------ fused kernel
// Requires D == 256, U % 128 == 0, T % 64 == 0.
#define TC 64    // timesteps per chunk
#define GN 128   // units per block

// Stage 2 rows (1 KB fp32 each) of the x-chunk into LDS as bf16 with the
// XOR-16B-chunk swizzle: LDS[row][q ^ (row&15)] = G[row][q], q = 16B chunk.
__device__ __forceinline__ void stage2(const float* __restrict__ g,
                                       char* lds, int row0, int lane)
{
    const int r = row0 + (lane >> 5);   // 32 lanes per row
    const int q = lane & 31;            // 32B global chunk -> 16B bf16 chunk
    const float* gp = g + (long)r * 256 + q * 8;
    float4 a  = *(const float4*)gp;
    float4 bq = *(const float4*)(gp + 4);
    union { __hip_bfloat162 h; unsigned u; } c0, c1, c2, c3;
    c0.h = __float22bfloat162_rn(make_float2(a.x, a.y));
    c1.h = __float22bfloat162_rn(make_float2(a.z, a.w));
    c2.h = __float22bfloat162_rn(make_float2(bq.x, bq.y));
    c3.h = __float22bfloat162_rn(make_float2(bq.z, bq.w));
    uint4 wv = {c0.u, c1.u, c2.u, c3.u};
    *(uint4*)(lds + (long)r * 512 + ((q ^ (r & 15)) << 4)) = wv;
}

__global__ __launch_bounds__(256, 1) void indrnn_fused(
    const float* __restrict__ x,             // fp32 [B*T, 256]
    const unsigned short* __restrict__ wt,   // bf16 [U, 256]  (W^T)
    const float* __restrict__ bias,          // [U]
    const float* __restrict__ h0,            // [B, U]
    const float* __restrict__ uvec,          // [U]
    float* __restrict__ out,                 // [B, T, U]
    int B, int T, int U)
{
    __shared__ __align__(16) char  Xa[2][TC * 512];  // 2 x 32 KB bf16 A-chunks
    __shared__ __align__(16) float P[TC * GN];       // 32 KB fp32 proj

    const int tid  = threadIdx.x;
    const int lane = tid & 63;
    const int w    = tid >> 6;     // wave 0..3
    const int m    = lane & 15;
    const int quad = lane >> 4;    // 0..3
    const int b    = blockIdx.x;
    const int n0   = blockIdx.y * GN;
    const int tq   = (w >> 1) * 32;   // wave's t quadrant (local)
    const int cq   = (w & 1) * 64;    // wave's unit quadrant

    // W fragments resident in registers (128 VGPRs), loaded once.
    // B-frag layout: n = n0+cq+j*16+m, k = kt*32 + quad*8 + e.
    bf16x8 bfr[4][8];
#pragma unroll
    for (int j = 0; j < 4; ++j)
#pragma unroll
        for (int kt = 0; kt < 8; ++kt)
            bfr[j][kt] = *(const bf16x8*)(
                wt + (long)(n0 + cq + j * 16 + m) * 256 + kt * 32 + quad * 8);

    float bb[4];
#pragma unroll
    for (int j = 0; j < 4; ++j) bb[j] = bias[n0 + cq + j * 16 + m];

    float uc = 0.0f, h = 0.0f;
    if (tid < GN) {
        uc = fminf(fmaxf(uvec[n0 + tid], 0.0f), 1.0f);
        h  = h0[(long)b * U + n0 + tid];
    }

    const float* xrow = x + (long)b * T * 256;

    // ---- prologue: all 4 waves stage chunk 0 (16 rows each)
#pragma unroll
    for (int p = 0; p < 8; ++p)
        stage2(xrow, Xa[0], w * 16 + p * 2, lane);

    const int nch = T / TC;
    for (int c = 0; c < nch; ++c) {
        char* Xc = Xa[c & 1];
        __syncthreads();   // Xa[c&1] staged; P free (prev scan done)

        // ---- MFMA: wave computes 32t x 64u quadrant; A from LDS, B from regs
        f32x4 acc[2][4];
#pragma unroll
        for (int i = 0; i < 2; ++i)
#pragma unroll
            for (int j = 0; j < 4; ++j) acc[i][j] = (f32x4){0.f, 0.f, 0.f, 0.f};

#pragma unroll
        for (int kt = 0; kt < 8; ++kt) {
            const int off = (((kt * 4 + quad) ^ m) << 4);
            bf16x8 a0 = *(const bf16x8*)(Xc + (tq + m) * 512 + off);
            bf16x8 a1 = *(const bf16x8*)(Xc + (tq + 16 + m) * 512 + off);
#pragma unroll
            for (int j = 0; j < 4; ++j) {
                acc[0][j] = __builtin_amdgcn_mfma_f32_16x16x32_bf16(
                    a0, bfr[j][kt], acc[0][j], 0, 0, 0);
                acc[1][j] = __builtin_amdgcn_mfma_f32_16x16x32_bf16(
                    a1, bfr[j][kt], acc[1][j], 0, 0, 0);
            }
        }

        // ---- proj (+bias) -> P, col-swizzled by quad (conflict-free)
#pragma unroll
        for (int i = 0; i < 2; ++i)
#pragma unroll
            for (int j = 0; j < 4; ++j)
#pragma unroll
                for (int r = 0; r < 4; ++r) {
                    int tl = tq + i * 16 + quad * 4 + r;
                    int cs = (cq + j * 16 + m) ^ (quad << 4);
                    P[tl * GN + cs] = acc[i][j][r] + bb[j];
                }
        __syncthreads();   // P visible; Xa[c&1] reads drained

        // ---- waves 2-3: stage+convert chunk c+1; waves 0-1: scan chunk c
        if (tid >= 128) {
            if (c + 1 < nch) {
                const float* gnext = xrow + (long)(c + 1) * TC * 256;
                char* Xn = Xa[(c + 1) & 1];
#pragma unroll
                for (int p = 0; p < 16; ++p)
                    stage2(gnext, Xn, (w - 2) * 32 + p * 2, lane);
            }
        } else {
            float* og = out + ((long)b * T + (long)c * TC) * U + n0 + tid;
#pragma unroll 8
            for (int t = 0; t < TC; ++t) {
                float pv = P[t * GN + (tid ^ (((t >> 2) & 3) << 4))];
                h = fmaxf(fmaf(h, uc, pv), 0.0f);
                og[(long)t * U] = h;
            }
        }
    }
}

// ------------------------------------------------------------ fp32 fallback
#define BM 128
#define BN 128
#define BK 8

__global__ __launch_bounds__(256) void indrnn_gemm_bias(
    const float* __restrict__ A, const float* __restrict__ Bm,
    const float* __restrict__ bias, float* __restrict__ C,
    int M, int N, int K)
{
    __shared__ float As[BK][BM];
    __shared__ float Bs[BK][BN];
    const int tid = threadIdx.x;
    const int row0 = blockIdx.x * BM, col0 = blockIdx.y * BN;
    const int tx = tid & 15, ty = tid >> 4;
    float acc[8][8];
#pragma unroll
    for (int i = 0; i < 8; ++i)
#pragma unroll
        for (int j = 0; j < 8; ++j) acc[i][j] = 0.0f;
    const int am = tid >> 1, ak = (tid & 1) * 4;
    const int bk = tid >> 5, bn = (tid & 31) * 4;
    const float* Aptr = A + (long)(row0 + am) * K + ak;
    const float* Bptr = Bm + (long)bk * N + col0 + bn;
    for (int kt = 0; kt < K; kt += BK) {
        float4 av = *(const float4*)(Aptr + kt);
        float4 bv = *(const float4*)(Bptr + (long)kt * N);
        As[ak + 0][am] = av.x; As[ak + 1][am] = av.y;
        As[ak + 2][am] = av.z; As[ak + 3][am] = av.w;
        *(float4*)&Bs[bk][bn] = bv;
        __syncthreads();
#pragma unroll
        for (int k = 0; k < BK; ++k) {
            float4 a0 = *(const float4*)&As[k][ty * 4];
            float4 a1 = *(const float4*)&As[k][64 + ty * 4];
            float4 b0 = *(const float4*)&Bs[k][tx * 4];
            float4 b1 = *(const float4*)&Bs[k][64 + tx * 4];
            float a[8] = {a0.x, a0.y, a0.z, a0.w, a1.x, a1.y, a1.z, a1.w};
            float bb2[8] = {b0.x, b0.y, b0.z, b0.w, b1.x, b1.y, b1.z, b1.w};
#pragma unroll
            for (int i = 0; i < 8; ++i)
#pragma unroll
                for (int j = 0; j < 8; ++j)
                    acc[i][j] = fmaf(a[i], bb2[j], acc[i][j]);
        }
        __syncthreads();
    }
    float bb[8];
#pragma unroll
    for (int j = 0; j < 4; ++j) {
        bb[j] = bias[col0 + tx * 4 + j];
        bb[j + 4] = bias[col0 + 64 + tx * 4 + j];
    }
#pragma unroll
    for (int i = 0; i < 8; ++i) {
        const int r = (i < 4) ? (ty * 4 + i) : (64 + ty * 4 + (i - 4));
        float* crow = C + (long)(row0 + r) * N + col0;
        float4 v0 = {acc[i][0] + bb[0], acc[i][1] + bb[1], acc[i][2] + bb[2], acc[i][3] + bb[3]};
        float4 v1 = {acc[i][4] + bb[4], acc[i][5] + bb[5], acc[i][6] + bb[6], acc[i][7] + bb[7]};
        *(float4*)(crow + tx * 4) = v0;
        *(float4*)(crow + 64 + tx * 4) = v1;
    }
}

#define SCAN_UNROLL 32

__global__ __launch_bounds__(256) void indrnn_scan(
    float* __restrict__ out, const float* __restrict__ h0,
    const float* __restrict__ u, int B, int T, int U)
{
    const int idx = blockIdx.x * blockDim.x + threadIdx.x;
    if (idx >= B * U) return;
    const int b = idx / U;
    const int un = idx - b * U;
    const float uc = fminf(fmaxf(u[un], 0.0f), 1.0f);
    float h = h0[(long)b * U + un];
    float* p = out + (long)b * T * U + un;
    for (int t = 0; t < T; t += SCAN_UNROLL) {
        float pv[SCAN_UNROLL];
#pragma unroll
        for (int i = 0; i < SCAN_UNROLL; ++i)
            pv[i] = p[(long)(t + i) * U];
#pragma unroll
        for (int i = 0; i < SCAN_UNROLL; ++i) {
            h = fmaxf(fmaf(h, uc, pv[i]), 0.0f);
            pv[i] = h;
        }
#pragma unroll
        for (int i = 0; i < SCAN_UNROLL; ++i)
            p[(long)(t + i) * U] = pv[i];
    }
}

// ------------------------------------------------------------ launch
extern "C" void kernel_launch(void* const* d_in, const int* in_sizes, int n_in,
                              void* d_out, int out_size, void* d_ws, size_t ws_size,
                              hipStream_t stream) {
    const float* x  = (const float*)d_in[0]; // [B,T,D]
    const float* h0 = (const float*)d_in[1]; // [B,U]
    const float* W  = (const float*)d_in[2]; // [D,U]
    const float* u  = (const float*)d_in[3]; // [U]
    const float* b  = (const float*)d_in[4]; // [U]
    float* out = (float*)d_out;              // [B,T,U]

    const int U = in_sizes[3];
    const int B = in_sizes[1] / U;
    const int D = in_sizes[2] / U;
    const int T = in_sizes[0] / (B * D);
    const int M = B * T;

    const size_t wt_bytes = (size_t)U * D * sizeof(unsigned short);
    const bool fused_ok = (D == 256) && (U % GN == 0) && (T % TC == 0) &&
                          (ws_size >= wt_bytes);

    if (fused_ok) {
        unsigned short* wt = (unsigned short*)d_ws;
        const int nwt = U * (D / 4);
        conv_wt<<<(nwt + 255) / 256, 256, 0, stream>>>(W, wt, D, U);

        dim3 g(B, U / GN);
        indrnn_fused<<<g, 256, 0, stream>>>(x, wt, b, h0, u, out, B, T, U);
    } else {
        dim3 ggrid(M / BM, U / BN);
        indrnn_gemm_bias<<<ggrid, 256, 0, stream>>>(x, W, b, out, M, U, D);
        const int nthreads = B * U;
        indrnn_scan<<<(nthreads + 255) / 256, 256, 0, stream>>>(out, h0, u, B, T, U);
    }
}

// Round 6
// 127.815 us; speedup vs baseline: 1.2710x; 1.2710x over previous
//
#include <hip/hip_runtime.h>

// IndRNN forward: proj = x @ W + b  (K=D=256), then
// h_t = relu(proj_t + h_{t-1} * clip(u,0,1)) over T.
// R6: GN=64, 2 blocks/CU (80 KB LDS). All structural pieces individually
//     proven: R4's 2-barrier separate-P chunk loop, R2/R3's fixed-trip
//     gl_lds16 staging by waves 2-3, wave-0 scan with PLAIN stores
//     (R5's nontemporal stores + variable-trip staging loops caused a
//     replay-only nondeterminism; both reverted).

__device__ __forceinline__ unsigned short f2bf(float f) {
    unsigned int u = __float_as_uint(f);
    unsigned int r = (u + 0x7FFF + ((u >> 16) & 1)) >> 16;  // RNE
    return (unsigned short)r;
}

typedef __bf16 bf16x8 __attribute__((ext_vector_type(8)));
typedef float f32x4 __attribute__((ext_vector_type(4)));

typedef const unsigned char __attribute__((address_space(1))) gc_t;
typedef unsigned char __attribute__((address_space(3))) lds_t;

__device__ __forceinline__ void gl_lds16(const void* g, void* l) {
    __builtin_amdgcn_global_load_lds((gc_t*)g, (lds_t*)l, 16, 0, 0);
}

// ------------------------------------------------------------ conversions
// One launch: x [M,256] fp32 -> bf16 (4 elems/thread), then W -> Wt bf16.
__global__ __launch_bounds__(256) void conv_xw(
    const float* __restrict__ x, unsigned short* __restrict__ xb, int nx4,
    const float* __restrict__ W, unsigned short* __restrict__ Wt, int K, int N)
{
    int i = blockIdx.x * blockDim.x + threadIdx.x;
    if (i < nx4) {
        float4 v = *(const float4*)(x + (long)i * 4);
        ushort4 o;
        o.x = f2bf(v.x); o.y = f2bf(v.y); o.z = f2bf(v.z); o.w = f2bf(v.w);
        *(ushort4*)(xb + (long)i * 4) = o;
        return;
    }
    int idx = i - nx4;
    int kq = K >> 2;
    if (idx >= N * kq) return;
    int n = idx / kq;
    int k4 = (idx - n * kq) * 4;
    ushort4 o;
    o.x = f2bf(W[(long)(k4 + 0) * N + n]);
    o.y = f2bf(W[(long)(k4 + 1) * N + n]);
    o.z = f2bf(W[(long)(k4 + 2) * N + n]);
    o.w = f2bf(W[(long)(k4 + 3) * N + n]);
    *(ushort4*)(Wt + (long)n * K + k4) = o;
}

// ------------------------------------------------------------ fused kernel
// Requires D == 256, U % 64 == 0, T % 64 == 0.
#define TC 64    // timesteps per chunk
#define GN 64    // units per block

__global__ __launch_bounds__(256, 2) void indrnn_fused(
    const unsigned short* __restrict__ xb,   // bf16 [B*T, 256]
    const unsigned short* __restrict__ wt,   // bf16 [U, 256]  (W^T)
    const float* __restrict__ bias,          // [U]
    const float* __restrict__ h0,            // [B, U]
    const float* __restrict__ uvec,          // [U]
    float* __restrict__ out,                 // [B, T, U]
    int B, int T, int U)
{
    __shared__ __align__(16) char  Xa[2][TC * 512];  // 2 x 32 KB bf16 A-chunks
    __shared__ __align__(16) float P[TC * GN];       // 16 KB fp32 proj

    const int tid  = threadIdx.x;
    const int lane = tid & 63;
    const int w    = tid >> 6;     // wave 0..3
    const int m    = lane & 15;
    const int quad = lane >> 4;    // 0..3
    const int b    = blockIdx.x;
    const int n0   = blockIdx.y * GN;
    const int tq   = w * 16;       // wave's 16-t stripe within the chunk

    // W fragments resident in registers (128 VGPRs/wave), loaded once.
    // B-frag layout (verified R2-R4): n = n0+j*16+m, k = kt*32 + quad*8 + e.
    bf16x8 bfr[4][8];
#pragma unroll
    for (int j = 0; j < 4; ++j)
#pragma unroll
        for (int kt = 0; kt < 8; ++kt)
            bfr[j][kt] = *(const bf16x8*)(
                wt + (long)(n0 + j * 16 + m) * 256 + kt * 32 + quad * 8);

    float bb[4];
#pragma unroll
    for (int j = 0; j < 4; ++j) bb[j] = bias[n0 + j * 16 + m];

    float uc = 0.0f, h = 0.0f;
    if (tid < GN) {
        uc = fminf(fmaxf(uvec[n0 + tid], 0.0f), 1.0f);
        h  = h0[(long)b * U + n0 + tid];
    }

    const unsigned short* xrow = xb + (long)b * T * 256;

    // ---- prologue: all 4 waves stage chunk 0 (fixed trip, R2/R3-proven).
    // Call covers rows 2*blk, 2*blk+1 (1 KB); lane: row = 2*blk + (lane>>5),
    // global 16B-chunk gp = (lane&31) ^ (row&15); LDS gets chunk (lane&31):
    // LDS[row][p] = G[row][p ^ (row&15)].
    {
        const int p = lane & 31, hh = lane >> 5;
#pragma unroll
        for (int i = 0; i < 8; ++i) {
            int blk = i * 4 + w;
            int r   = 2 * blk + hh;
            int gp  = p ^ (r & 15);
            gl_lds16(xrow + (long)r * 256 + gp * 8, &Xa[0][blk * 1024]);
        }
    }

    const int nch = T / TC;
    for (int c = 0; c < nch; ++c) {
        const char* Xc = Xa[c & 1];
        __syncthreads();   // stage(c) drained (barrier waits vmcnt); P free

        // ---- MFMA: each wave 16t x 64u; A from LDS (swizzled), B from regs
        f32x4 acc[4];
#pragma unroll
        for (int j = 0; j < 4; ++j) acc[j] = (f32x4){0.f, 0.f, 0.f, 0.f};

#pragma unroll
        for (int kt = 0; kt < 8; ++kt) {
            bf16x8 a = *(const bf16x8*)(
                Xc + (tq + m) * 512 + (((kt * 4 + quad) ^ m) << 4));
#pragma unroll
            for (int j = 0; j < 4; ++j)
                acc[j] = __builtin_amdgcn_mfma_f32_16x16x32_bf16(
                    a, bfr[j][kt], acc[j], 0, 0, 0);
        }

        // ---- proj (+bias) -> P, col XOR-swizzled by quad (2-way, free)
        // C/D layout: col = m, row = quad*4 + r (verified R2-R4)
#pragma unroll
        for (int j = 0; j < 4; ++j)
#pragma unroll
            for (int r = 0; r < 4; ++r) {
                int tl = tq + quad * 4 + r;
                int cs = (j * 16 + m) ^ (quad << 4);
                P[tl * GN + cs] = acc[j][r] + bb[j];
            }
        __syncthreads();   // P visible; Xc reads drained

        // ---- waves 2-3: stage chunk c+1 (R2/R3-proven fixed pattern);
        //      wave 0: scan chunk c (plain stores); wave 1: idle
        if (w >= 2) {
            if (c + 1 < nch) {
                const unsigned short* gb = xrow + (long)(c + 1) * TC * 256;
                char* Xn = Xa[(c + 1) & 1];
                const int p = lane & 31, hh = lane >> 5;
#pragma unroll
                for (int i = 0; i < 16; ++i) {
                    int blk = i * 2 + (w - 2);
                    int r   = 2 * blk + hh;
                    int gp  = p ^ (r & 15);
                    gl_lds16(gb + (long)r * 256 + gp * 8, Xn + blk * 1024);
                }
            }
        } else if (w == 0) {
            float* og = out + ((long)b * T + (long)c * TC) * U + n0 + lane;
#pragma unroll 16
            for (int t = 0; t < TC; ++t) {
                float pv = P[t * GN + (lane ^ (((t >> 2) & 3) << 4))];
                h = fmaxf(fmaf(h, uc, pv), 0.0f);
                og[(long)t * U] = h;
            }
        }
    }
}

// ------------------------------------------------------------ fp32 fallback
#define BM 128
#define BN 128
#define BK 8

__global__ __launch_bounds__(256) void indrnn_gemm_bias(
    const float* __restrict__ A, const float* __restrict__ Bm,
    const float* __restrict__ bias, float* __restrict__ C,
    int M, int N, int K)
{
    __shared__ float As[BK][BM];
    __shared__ float Bs[BK][BN];
    const int tid = threadIdx.x;
    const int row0 = blockIdx.x * BM, col0 = blockIdx.y * BN;
    const int tx = tid & 15, ty = tid >> 4;
    float acc[8][8];
#pragma unroll
    for (int i = 0; i < 8; ++i)
#pragma unroll
        for (int j = 0; j < 8; ++j) acc[i][j] = 0.0f;
    const int am = tid >> 1, ak = (tid & 1) * 4;
    const int bk = tid >> 5, bn = (tid & 31) * 4;
    const float* Aptr = A + (long)(row0 + am) * K + ak;
    const float* Bptr = Bm + (long)bk * N + col0 + bn;
    for (int kt = 0; kt < K; kt += BK) {
        float4 av = *(const float4*)(Aptr + kt);
        float4 bv = *(const float4*)(Bptr + (long)kt * N);
        As[ak + 0][am] = av.x; As[ak + 1][am] = av.y;
        As[ak + 2][am] = av.z; As[ak + 3][am] = av.w;
        *(float4*)&Bs[bk][bn] = bv;
        __syncthreads();
#pragma unroll
        for (int k = 0; k < BK; ++k) {
            float4 a0 = *(const float4*)&As[k][ty * 4];
            float4 a1 = *(const float4*)&As[k][64 + ty * 4];
            float4 b0 = *(const float4*)&Bs[k][tx * 4];
            float4 b1 = *(const float4*)&Bs[k][64 + tx * 4];
            float a[8] = {a0.x, a0.y, a0.z, a0.w, a1.x, a1.y, a1.z, a1.w};
            float bb2[8] = {b0.x, b0.y, b0.z, b0.w, b1.x, b1.y, b1.z, b1.w};
#pragma unroll
            for (int i = 0; i < 8; ++i)
#pragma unroll
                for (int j = 0; j < 8; ++j)
                    acc[i][j] = fmaf(a[i], bb2[j], acc[i][j]);
        }
        __syncthreads();
    }
    float bb[8];
#pragma unroll
    for (int j = 0; j < 4; ++j) {
        bb[j] = bias[col0 + tx * 4 + j];
        bb[j + 4] = bias[col0 + 64 + tx * 4 + j];
    }
#pragma unroll
    for (int i = 0; i < 8; ++i) {
        const int r = (i < 4) ? (ty * 4 + i) : (64 + ty * 4 + (i - 4));
        float* crow = C + (long)(row0 + r) * N + col0;
        float4 v0 = {acc[i][0] + bb[0], acc[i][1] + bb[1], acc[i][2] + bb[2], acc[i][3] + bb[3]};
        float4 v1 = {acc[i][4] + bb[4], acc[i][5] + bb[5], acc[i][6] + bb[6], acc[i][7] + bb[7]};
        *(float4*)(crow + tx * 4) = v0;
        *(float4*)(crow + 64 + tx * 4) = v1;
    }
}

#define SCAN_UNROLL 32

__global__ __launch_bounds__(256) void indrnn_scan(
    float* __restrict__ out, const float* __restrict__ h0,
    const float* __restrict__ u, int B, int T, int U)
{
    const int idx = blockIdx.x * blockDim.x + threadIdx.x;
    if (idx >= B * U) return;
    const int b = idx / U;
    const int un = idx - b * U;
    const float uc = fminf(fmaxf(u[un], 0.0f), 1.0f);
    float h = h0[(long)b * U + un];
    float* p = out + (long)b * T * U + un;
    for (int t = 0; t < T; t += SCAN_UNROLL) {
        float pv[SCAN_UNROLL];
#pragma unroll
        for (int i = 0; i < SCAN_UNROLL; ++i)
            pv[i] = p[(long)(t + i) * U];
#pragma unroll
        for (int i = 0; i < SCAN_UNROLL; ++i) {
            h = fmaxf(fmaf(h, uc, pv[i]), 0.0f);
            pv[i] = h;
        }
#pragma unroll
        for (int i = 0; i < SCAN_UNROLL; ++i)
            p[(long)(t + i) * U] = pv[i];
    }
}

// ------------------------------------------------------------ launch
extern "C" void kernel_launch(void* const* d_in, const int* in_sizes, int n_in,
                              void* d_out, int out_size, void* d_ws, size_t ws_size,
                              hipStream_t stream) {
    const float* x  = (const float*)d_in[0]; // [B,T,D]
    const float* h0 = (const float*)d_in[1]; // [B,U]
    const float* W  = (const float*)d_in[2]; // [D,U]
    const float* u  = (const float*)d_in[3]; // [U]
    const float* b  = (const float*)d_in[4]; // [U]
    float* out = (float*)d_out;              // [B,T,U]

    const int U = in_sizes[3];
    const int B = in_sizes[1] / U;
    const int D = in_sizes[2] / U;
    const int T = in_sizes[0] / (B * D);
    const int M = B * T;

    const size_t xb_bytes = (size_t)M * D * sizeof(unsigned short);
    const size_t wt_bytes = (size_t)U * D * sizeof(unsigned short);
    const bool fused_ok = (D == 256) && (U % GN == 0) && (T % TC == 0) &&
                          (ws_size >= xb_bytes + wt_bytes);

    if (fused_ok) {
        unsigned short* xb = (unsigned short*)d_ws;
        unsigned short* wt = (unsigned short*)((char*)d_ws + xb_bytes);

        const int nx4 = (M * D) / 4;
        const int nwt = U * (D / 4);
        const int ntot = nx4 + nwt;
        conv_xw<<<(ntot + 255) / 256, 256, 0, stream>>>(x, xb, nx4, W, wt, D, U);

        dim3 g(B, U / GN);
        indrnn_fused<<<g, 256, 0, stream>>>(xb, wt, b, h0, u, out, B, T, U);
    } else {
        dim3 ggrid(M / BM, U / BN);
        indrnn_gemm_bias<<<ggrid, 256, 0, stream>>>(x, W, b, out, M, U, D);
        const int nthreads = B * U;
        indrnn_scan<<<(nthreads + 255) / 256, 256, 0, stream>>>(out, h0, u, B, T, U);
    }
}